// Round 8
// baseline (112.692 us; speedup 1.0000x reference)
//
#include <hip/hip_runtime.h>
#include <hip/hip_bf16.h>

using floatx4 = __attribute__((ext_vector_type(4))) float;
using int4v   = __attribute__((ext_vector_type(4))) int;
using int8v   = __attribute__((ext_vector_type(8))) int;

#define TEMP_INV 14.285714285714286f  // 1/0.07
#define DD 256    // feature dim; one fp8 row = 256 B
#define BROWS 64  // rows per gemm block
#define BNC 64    // cols per ct tile
#define NCT 16    // col tiles/block -> block col span 1024; gridDim.x = 8 = XCD
#define SC1 127   // e8m0 exponent 127 -> scale 1.0

// ---- kernel 1: L2 normalize -> fp8 e4m3 + exact fp8 diag dot + out zero ----
// 256 thr / 16 rows per block; thread (r = t>>4, s = t&15) owns bytes
// [s*16, s*16+16) of row blockIdx.x*16 + r. Fragment-major p8 destination of
// those 16 bytes is one contiguous 16-B chunk (64-B coalesced across lanes).
__global__ __launch_bounds__(256) void nrm_kernel(
    const float* __restrict__ anchor, const float* __restrict__ positive,
    unsigned char* __restrict__ a8, unsigned char* __restrict__ p8,
    float* __restrict__ diag, float* __restrict__ out) {
  if (blockIdx.x == 0 && threadIdx.x == 0) out[0] = 0.f;  // stream-order visible
  const int t = threadIdx.x;
  const int s = t & 15;               // 16-float segment within the row
  const int r = t >> 4;               // row within the 16-row group
  const int row = blockIdx.x * 16 + r;
  const float4* av = (const float4*)(anchor   + (size_t)row * DD + s * 16);
  const float4* pv = (const float4*)(positive + (size_t)row * DD + s * 16);
  float4 va[4], vp[4];
  float sa = 0.f, sp = 0.f;
#pragma unroll
  for (int k = 0; k < 4; ++k) {
    va[k] = av[k]; vp[k] = pv[k];
    sa += va[k].x * va[k].x + va[k].y * va[k].y + va[k].z * va[k].z + va[k].w * va[k].w;
    sp += vp[k].x * vp[k].x + vp[k].y * vp[k].y + vp[k].z * vp[k].z + vp[k].w * vp[k].w;
  }
  // reduce over the 16 threads of this row (lanes (r&3)*16 + s, s=0..15)
#pragma unroll
  for (int m = 1; m < 16; m <<= 1) {
    sa += __shfl_xor(sa, m, 16);
    sp += __shfl_xor(sp, m, 16);
  }
  const float ka = 1.0f / fmaxf(sqrtf(sa), 1e-12f);
  const float kp = 1.0f / fmaxf(sqrtf(sp), 1e-12f);
  int pa[4], pq[4];
#pragma unroll
  for (int k = 0; k < 4; ++k) {
    int x = __builtin_amdgcn_cvt_pk_fp8_f32(va[k].x * ka, va[k].y * ka, 0, false);
    pa[k] = __builtin_amdgcn_cvt_pk_fp8_f32(va[k].z * ka, va[k].w * ka, x, true);
    int y = __builtin_amdgcn_cvt_pk_fp8_f32(vp[k].x * kp, vp[k].y * kp, 0, false);
    pq[k] = __builtin_amdgcn_cvt_pk_fp8_f32(vp[k].z * kp, vp[k].w * kp, y, true);
  }
  // a8 row-major, 16 B/thread, coalesced
  *(int4v*)(a8 + (size_t)row * DD + s * 16) = (int4v){pa[0], pa[1], pa[2], pa[3]};
  // p8 fragment-major, 16 B/thread, 64-B-coalesced across lanes
  {
    const unsigned int off = (unsigned)blockIdx.x * 4096 + ((s >> 3) << 11)
                           + ((s & 1) << 10) + (((s >> 1) & 3) << 8) + (r << 4);
    *(int4v*)(p8 + off) = (int4v){pq[0], pq[1], pq[2], pq[3]};
  }
  // exact quantized dot partial over this thread's 16 elements
  float d = 0.f;
#pragma unroll
  for (int k = 0; k < 4; ++k) {
    d += __builtin_amdgcn_cvt_f32_fp8(pa[k], 0) * __builtin_amdgcn_cvt_f32_fp8(pq[k], 0)
       + __builtin_amdgcn_cvt_f32_fp8(pa[k], 1) * __builtin_amdgcn_cvt_f32_fp8(pq[k], 1)
       + __builtin_amdgcn_cvt_f32_fp8(pa[k], 2) * __builtin_amdgcn_cvt_f32_fp8(pq[k], 2)
       + __builtin_amdgcn_cvt_f32_fp8(pa[k], 3) * __builtin_amdgcn_cvt_f32_fp8(pq[k], 3);
  }
#pragma unroll
  for (int m = 1; m < 16; m <<= 1) d += __shfl_xor(d, m, 16);
  if (s == 0) diag[row] = d;
}

// A fragment straight from global (row-major, per-lane gather, once/kernel).
__device__ __forceinline__ int8v fragG(const unsigned char* g) {
  const int4v lo = *(const int4v*)(g);
  const int4v hi = *(const int4v*)(g + 16);
  return __builtin_shufflevector(lo, hi, 0, 1, 2, 3, 4, 5, 6, 7);
}

__device__ __forceinline__ floatx4 mfma_sc(int8v a, int8v b, floatx4 c) {
  return __builtin_amdgcn_mfma_scale_f32_16x16x128_f8f6f4(a, b, c, 0, 0, 0,
                                                          SC1, 0, SC1);
}

// Load the 4 B-fragments of column tile ct into buf (8 x global_load_dwordx4,
// each 1 KB/wave contiguous in fragment-major p8).
#define LOADF(ct, buf)                                                        \
  {                                                                           \
    const unsigned char* bb_ = bbase + (size_t)(ct) * (BNC * DD);             \
    _Pragma("unroll") for (int ks_ = 0; ks_ < 2; ++ks_)                       \
    _Pragma("unroll") for (int ni_ = 0; ni_ < 2; ++ni_) {                     \
      const unsigned char* c_ = bb_ + ni_ * 4096 + ks_ * 2048;                \
      const int4v lo_ = *(const int4v*)(c_);                                  \
      const int4v hi_ = *(const int4v*)(c_ + 1024);                           \
      buf[ks_][ni_] =                                                         \
          __builtin_shufflevector(lo_, hi_, 0, 1, 2, 3, 4, 5, 6, 7);          \
    }                                                                         \
  }

// MFMA cluster + fused stats epilogue for tile ct from buf.
#define COMPUTE(ct, buf)                                                      \
  {                                                                           \
    floatx4 acc[2][2];                                                        \
    _Pragma("unroll") for (int a_ = 0; a_ < 2; ++a_)                          \
    _Pragma("unroll") for (int b_ = 0; b_ < 2; ++b_)                          \
        acc[a_][b_] = (floatx4){0.f, 0.f, 0.f, 0.f};                          \
    _Pragma("unroll") for (int ks_ = 0; ks_ < 2; ++ks_)                       \
    _Pragma("unroll") for (int ni_ = 0; ni_ < 2; ++ni_) {                     \
      acc[0][ni_] = mfma_sc(a_frag[0][ks_], buf[ks_][ni_], acc[0][ni_]);      \
      acc[1][ni_] = mfma_sc(a_frag[1][ks_], buf[ks_][ni_], acc[1][ni_]);      \
    }                                                                         \
    const int col0_ = colbase + (ct) * BNC;                                   \
    const bool hd_ = hdbase && ((int)(blockIdx.y & 15) == (ct));              \
    if (!hd_) {                                                               \
      _Pragma("unroll") for (int mi_ = 0; mi_ < 2; ++mi_)                     \
      _Pragma("unroll") for (int rg_ = 0; rg_ < 4; ++rg_)                     \
      _Pragma("unroll") for (int ni_ = 0; ni_ < 2; ++ni_) {                   \
        const float s_ = acc[mi_][ni_][rg_];                                  \
        se_run[mi_][rg_] += __expf(s_ * TEMP_INV);                            \
        mx_run[mi_][rg_] = fmaxf(mx_run[mi_][rg_], s_);                       \
      }                                                                       \
    } else {                                                                  \
      _Pragma("unroll") for (int mi_ = 0; mi_ < 2; ++mi_)                     \
      _Pragma("unroll") for (int rg_ = 0; rg_ < 4; ++rg_) {                   \
        const int i_ = row0 + wm * 32 + mi_ * 16 + quad * 4 + rg_;            \
        _Pragma("unroll") for (int ni_ = 0; ni_ < 2; ++ni_) {                 \
          const float s_ = acc[mi_][ni_][rg_];                                \
          const int j_ = col0_ + wn * 32 + ni_ * 16 + l16;                    \
          se_run[mi_][rg_] += __expf(s_ * TEMP_INV);                          \
          mx_run[mi_][rg_] = fmaxf(mx_run[mi_][rg_], (i_ == j_) ? -INFINITY : s_); \
        }                                                                     \
      }                                                                       \
    }                                                                         \
  }

// ------ kernel 2: 256 thr / 4 waves; wave = 32x32; block = 64 rows x 64 cols,
// 16 column tiles. NEW vs R7: 1-tile-deep REGISTER PREFETCH of B fragments
// (two named buffers, manual 2x alternation -> no copies, static indexing).
// Loads for ct+1 issue BEFORE ct's MFMA cluster; no barriers anywhere, so the
// compiler's counted vmcnt keeps them in flight under the full compute+exp
// epilogue (~600 cyc coverage vs ~250 cyc L2 latency) -- the per-wave
// VMEM->MFMA dependency chain that every prior round left exposed.
// gridDim.x = 8 keeps col-group == XCD (worth ~20 us, R0-vs-R3).
// __launch_bounds__(256,4): budget 128 (the one proven non-pathological cap);
// working set ~114 -> no spill, 4 waves/SIMD = 16 waves/CU.
__global__ __launch_bounds__(256, 4) void gemm_stats(
    const unsigned char* __restrict__ a8, const unsigned char* __restrict__ p8,
    float* __restrict__ rsum, float* __restrict__ rmax, int Btot) {
  __shared__ float red_sum[2][BROWS];
  __shared__ float red_max[2][BROWS];

  const int t = threadIdx.x;
  const int wave = t >> 6, lane = t & 63;
  const int wm = wave & 1, wn = wave >> 1;      // 2 row-groups x 2 col-groups
  const int quad = lane >> 4, l16 = lane & 15;
  const int row0    = blockIdx.y * BROWS;
  const int colbase = blockIdx.x * (NCT * BNC);
  const bool hdbase = ((int)(blockIdx.y >> 4) == (int)blockIdx.x);

  // ---- A fragments: 16 VGPRs, ct-invariant ----
  // rows row0 + wm*32 + mi*16 + l16, K bytes [ks*128 + quad*32, +32)
  int8v a_frag[2][2];
  {
    const unsigned char* ab =
        a8 + (size_t)(row0 + wm * 32 + l16) * DD + quad * 32;
#pragma unroll
    for (int mi = 0; mi < 2; ++mi)
#pragma unroll
      for (int ks = 0; ks < 2; ++ks)
        a_frag[mi][ks] = fragG(ab + mi * 16 * DD + ks * 128);
  }

  // fragment-major base for this wave's col rows (16-aligned X -> X*256)
  const unsigned char* bbase =
      p8 + (size_t)(colbase + wn * 32) * DD + lane * 16;

  float se_run[2][4], mx_run[2][4];
#pragma unroll
  for (int a = 0; a < 2; ++a)
#pragma unroll
    for (int b = 0; b < 4; ++b) { se_run[a][b] = 0.f; mx_run[a][b] = -INFINITY; }

  int8v b0[2][2], b1[2][2];
  LOADF(0, b0);
  for (int ct2 = 0; ct2 < NCT / 2; ++ct2) {
    const int cta = 2 * ct2, ctb = 2 * ct2 + 1;
    LOADF(ctb, b1);                    // prefetch odd tile over even compute
    COMPUTE(cta, b0);
    if (ctb + 1 < NCT) LOADF(ctb + 1, b0);  // prefetch next even tile
    COMPUTE(ctb, b1);
  }

  // 16-lane cross reduction, then cross-wn combine via 1 KB LDS
#pragma unroll
  for (int mi = 0; mi < 2; ++mi) {
#pragma unroll
    for (int reg = 0; reg < 4; ++reg) {
      float se = se_run[mi][reg], mx = mx_run[mi][reg];
#pragma unroll
      for (int m = 1; m < 16; m <<= 1) {
        se += __shfl_xor(se, m, 64);
        mx = fmaxf(mx, __shfl_xor(mx, m, 64));
      }
      if (l16 == 0) {
        const int rb = wm * 32 + mi * 16 + quad * 4 + reg;
        red_sum[wn][rb] = se;
        red_max[wn][rb] = mx;
      }
    }
  }
  __syncthreads();
  if (t < BROWS) {
    rsum[(size_t)blockIdx.x * Btot + row0 + t] = red_sum[0][t] + red_sum[1][t];
    rmax[(size_t)blockIdx.x * Btot + row0 + t] =
        fmaxf(red_max[0][t], red_max[1][t]);
  }
}

// ---- kernel 3: per-row loss from partials, block-reduce, atomic mean ----
__global__ __launch_bounds__(256) void row_loss_kernel(
    const float* __restrict__ rsum, const float* __restrict__ rmax,
    const float* __restrict__ diag, float* __restrict__ out, int Btot, int NG) {
  const int i = blockIdx.x * 256 + threadIdx.x;
  float s = 0.f, m = -INFINITY;
  for (int c = 0; c < NG; ++c) {
    s += rsum[(size_t)c * Btot + i];
    m = fmaxf(m, rmax[(size_t)c * Btot + i]);
  }
  float rl = __logf(s + __expf(m * TEMP_INV)) - diag[i] * TEMP_INV;
#pragma unroll
  for (int mm = 32; mm >= 1; mm >>= 1) rl += __shfl_xor(rl, mm, 64);
  __shared__ float red[4];
  if ((threadIdx.x & 63) == 0) red[threadIdx.x >> 6] = rl;
  __syncthreads();
  if (threadIdx.x == 0)
    atomicAdd(out, (red[0] + red[1] + red[2] + red[3]) / (float)Btot);
}

extern "C" void kernel_launch(void* const* d_in, const int* in_sizes, int n_in,
                              void* d_out, int out_size, void* d_ws, size_t ws_size,
                              hipStream_t stream) {
  const float* anchor   = (const float*)d_in[0];
  const float* positive = (const float*)d_in[1];
  const int B  = in_sizes[0] / DD;     // 8192
  const int NG = B / (BNC * NCT);      // 8 column groups
  const size_t BD = (size_t)B * DD;

  // ws: a8(2MB) | p8(2MB, fragment-major) | rsum(NG*B) | rmax(NG*B) | diag(B)
  unsigned char* a8 = (unsigned char*)d_ws;
  unsigned char* p8 = a8 + BD;
  float* rsum  = (float*)(p8 + BD);
  float* rmax  = rsum + (size_t)NG * B;
  float* diag  = rmax + (size_t)NG * B;

  nrm_kernel<<<B / 16, 256, 0, stream>>>(anchor, positive, a8, p8, diag,
                                         (float*)d_out);
  dim3 g2(NG, B / BROWS);
  gemm_stats<<<g2, 256, 0, stream>>>(a8, p8, rsum, rmax, B);
  row_loss_kernel<<<B / 256, 256, 0, stream>>>(rsum, rmax, diag, (float*)d_out, B, NG);
}